// Round 13
// baseline (311.665 us; speedup 1.0000x reference)
//
#include <hip/hip_runtime.h>
#include <math.h>

// GCN forward: coarse-bucket counting-sort CSR + node-parallel bf16 gather.
// Measured models (R4-R12):
//   - device-scope atomic ~= 35B fabric + ~41ns, invariant to locality ->
//     minimize atomic COUNT (k_bin: 1 reservation per block-bucket).
//   - k_bin traffic = fragment count -> coarse buckets (196 x 512 nodes).
//   - gather must be node-parallel; bf16 rows = 64B/edge; random reads over
//     the 6.4MB table thrash 4MB XCD L2 (R12: FETCH 99MB per gather).
//   - R12 gemm1: 32-lane-broadcast x loads = 32B useful/instr, 72.8us ->
//     THIS ROUND: row-per-thread gemm1 (lane streams own row, W1 LDS-bcast).
//   - gathers: cooperative esrc loads (1 coalesced load + shfl per 16 edges)
//     to halve vmem instruction count.
// Pipeline: k_bin -> k_bukscan -> k_place -> k_gemm1 -> k_gather_fuse
//   (layer1 gather + ReLU + W2 via shfl, writes hWs2 bf16) -> k_gather_score
//   (layer2 gather + score head) -> 3-kernel online softmax.

static inline int cdiv(long a, int b) { return (int)((a + (long)b - 1) / b); }

#define EPB 8192      // edges per k_bin block (391 blocks @ E=3.2M)
#define NBMAX 256     // max buckets (N <= 131072 @ 512 nodes/bucket)
#define CAP 17408     // per-bucket capacity; mean 16384, +8 sigma

typedef unsigned short u16;
typedef int iv4 __attribute__((ext_vector_type(4)));

__device__ __forceinline__ u16 f2bf(float f) {  // RNE f32->bf16
  unsigned u = __float_as_uint(f);
  return (u16)((u + 0x7FFFu + ((u >> 16) & 1u)) >> 16);
}
__device__ __forceinline__ float bf2f(u16 h) {
  return __uint_as_float(((unsigned)h) << 16);
}

// --- binning: LDS hist -> one reservation atomic per (block,bucket) -> fill runs
__global__ __launch_bounds__(256) void k_bin(const int* __restrict__ src,
                                             const int* __restrict__ dst,
                                             unsigned* __restrict__ gcur,
                                             unsigned* __restrict__ ebuf,
                                             int E, int nbuk) {
  __shared__ unsigned lhist[NBMAX];
  __shared__ unsigned lcur[NBMAX];
  int tid = threadIdx.x;
  for (int i = tid; i < nbuk; i += 256) lhist[i] = 0;
  __syncthreads();
  int e0 = blockIdx.x * EPB, e1 = min(e0 + EPB, E);
  int nvec = (e1 - e0) >> 10;  // 1024-edge chunks (256 thr x 4)
  for (int k = 0; k < nvec; ++k) {
    iv4 d4 = __builtin_nontemporal_load((const iv4*)(dst + e0 + (k << 10) + tid * 4));
    atomicAdd(&lhist[d4.x >> 9], 1u);
    atomicAdd(&lhist[d4.y >> 9], 1u);
    atomicAdd(&lhist[d4.z >> 9], 1u);
    atomicAdd(&lhist[d4.w >> 9], 1u);
  }
  for (int e = e0 + (nvec << 10) + tid; e < e1; e += 256)
    atomicAdd(&lhist[__builtin_nontemporal_load(&dst[e]) >> 9], 1u);
  __syncthreads();
  for (int b = tid; b < nbuk; b += 256) {
    unsigned nn = lhist[b];
    lcur[b] = nn ? atomicAdd(&gcur[b], nn) : 0u;  // run reservation
  }
  __syncthreads();
  for (int k = 0; k < nvec; ++k) {
    int base = e0 + (k << 10) + tid * 4;
    iv4 d4 = __builtin_nontemporal_load((const iv4*)(dst + base));
    iv4 s4 = __builtin_nontemporal_load((const iv4*)(src + base));
#define PUT(dd, ss)                                              \
    {                                                            \
      int bb = (dd) >> 9;                                        \
      unsigned off = atomicAdd(&lcur[bb], 1u);                   \
      if (off < CAP)                                             \
        ebuf[(size_t)bb * CAP + off] =                           \
            ((unsigned)((dd) & 511) << 17) | (unsigned)(ss);     \
    }
    PUT(d4.x, s4.x) PUT(d4.y, s4.y) PUT(d4.z, s4.z) PUT(d4.w, s4.w)
  }
  for (int e = e0 + (nvec << 10) + tid; e < e1; e += 256) {
    int d = __builtin_nontemporal_load(&dst[e]);
    int s = __builtin_nontemporal_load(&src[e]);
    PUT(d, s)
  }
#undef PUT
}

// --- exclusive scan of bucket counts (one block; nbuk <= 256)
__global__ __launch_bounds__(256) void k_bukscan(const unsigned* __restrict__ gcur,
                                                 unsigned* __restrict__ bbase,
                                                 int* __restrict__ rowptr,
                                                 int nbuk, int N) {
  __shared__ unsigned sm[256];
  int t = threadIdx.x;
  unsigned v = (t < nbuk) ? min(gcur[t], (unsigned)CAP) : 0u;
  sm[t] = v;
  __syncthreads();
  for (int o = 1; o < 256; o <<= 1) {
    unsigned add = (t >= o) ? sm[t - o] : 0u;
    __syncthreads();
    sm[t] += add;
    __syncthreads();
  }
  if (t < nbuk) bbase[t] = sm[t] - v;  // exclusive
  if (t == 255) rowptr[N] = (int)sm[255];
}

// --- per-bucket (512 nodes): LDS count+scan -> rowptr/dinv; sort run into esrc.
__global__ __launch_bounds__(512) void k_place(const unsigned* __restrict__ gcur,
                                               const unsigned* __restrict__ ebuf,
                                               const unsigned* __restrict__ bbase,
                                               int* __restrict__ rowptr,
                                               float* __restrict__ dinv,
                                               int* __restrict__ esrc, int N) {
  __shared__ unsigned lcnt[512];
  __shared__ unsigned lofs[512];
  int b = blockIdx.x, tid = threadIdx.x;
  lcnt[tid] = 0;
  __syncthreads();
  int cnt = min((int)gcur[b], CAP);
  const unsigned* eb = ebuf + (size_t)b * CAP;
  for (int j = tid; j < cnt; j += 512) atomicAdd(&lcnt[eb[j] >> 17], 1u);
  __syncthreads();
  unsigned myc = lcnt[tid];
  lofs[tid] = myc;
  __syncthreads();
  for (int o = 1; o < 512; o <<= 1) {  // inclusive scan over 512
    unsigned add = (tid >= o) ? lofs[tid - o] : 0u;
    __syncthreads();
    lofs[tid] += add;
    __syncthreads();
  }
  unsigned base = bbase[b];
  unsigned ex = lofs[tid] - myc;  // exclusive (own entry only)
  int node = (b << 9) + tid;
  if (node < N) {
    rowptr[node] = (int)(base + ex);
    dinv[node] = rsqrtf((float)myc + 1.0f);  // deg = cnt + self-loop
  }
  lofs[tid] = ex;  // reuse as cursor
  __syncthreads();
  for (int j = tid; j < cnt; j += 512) {
    unsigned p = eb[j];
    unsigned r = atomicAdd(&lofs[p >> 17], 1u);  // LDS atomic
    esrc[base + r] = (int)(p & 0x1FFFF);
  }
}

// hWs = bf16(dinv[r] * (x @ W1)); ONE THREAD PER ROW, 32 accumulators.
// x: lane streams its own 512B row (sequential float4, full line use);
// W1 broadcast from LDS (same-address float4 reads are conflict-free).
__global__ __launch_bounds__(256) void k_gemm1(
    const float* __restrict__ x, const float* __restrict__ W1,
    const float* __restrict__ dinv, u16* __restrict__ hWs, int N) {
  __shared__ float4 w[128 * 8];  // w[k][q] = W1[k][4q..4q+3]
  for (int i = threadIdx.x; i < 1024; i += 256) w[i] = ((const float4*)W1)[i];
  __syncthreads();
  int r = blockIdx.x * 256 + threadIdx.x;
  if (r >= N) return;
  const float4* xr = (const float4*)(x + (size_t)r * 128);
  float acc[32];
#pragma unroll
  for (int c = 0; c < 32; ++c) acc[c] = 0.f;
  for (int k4 = 0; k4 < 32; ++k4) {
    float4 xv = xr[k4];
#pragma unroll
    for (int kk = 0; kk < 4; ++kk) {
      float xk = (kk == 0) ? xv.x : (kk == 1) ? xv.y : (kk == 2) ? xv.z : xv.w;
      const float4* wk = &w[(k4 * 4 + kk) * 8];
#pragma unroll
      for (int q = 0; q < 8; ++q) {
        float4 wv = wk[q];
        acc[q * 4 + 0] = fmaf(xk, wv.x, acc[q * 4 + 0]);
        acc[q * 4 + 1] = fmaf(xk, wv.y, acc[q * 4 + 1]);
        acc[q * 4 + 2] = fmaf(xk, wv.z, acc[q * 4 + 2]);
        acc[q * 4 + 3] = fmaf(xk, wv.w, acc[q * 4 + 3]);
      }
    }
  }
  float dv = dinv[r];
  unsigned pk[16];
#pragma unroll
  for (int q = 0; q < 16; ++q) {
    unsigned lo = f2bf(dv * acc[2 * q]);
    unsigned hi = f2bf(dv * acc[2 * q + 1]);
    pk[q] = lo | (hi << 16);
  }
  uint4* o4 = (uint4*)(hWs + (size_t)r * 32);
  o4[0] = make_uint4(pk[0], pk[1], pk[2], pk[3]);
  o4[1] = make_uint4(pk[4], pk[5], pk[6], pk[7]);
  o4[2] = make_uint4(pk[8], pk[9], pk[10], pk[11]);
  o4[3] = make_uint4(pk[12], pk[13], pk[14], pk[15]);
}

// layer-1 gather fused with layer-2 transform. 32 lanes/node, lane = column.
// Edge indices fetched cooperatively: 1 coalesced load + shfl per 16 edges.
//   r_c = relu(b1[c] + dinv_i*(hWs1[i,c] + sum_s hWs1[s,c]))
//   hWs2[i,c] = bf16(dinv_i * sum_k r_k * W2[k,c])
__global__ __launch_bounds__(256) void k_gather_fuse(
    const int* __restrict__ esrc, const int* __restrict__ rowptr,
    const float* __restrict__ dinv, const u16* __restrict__ hWs1,
    const float* __restrict__ b1, const float* __restrict__ W2,
    u16* __restrict__ hWs2, int N) {
  __shared__ float w2[32 * 32];
  for (int i = threadIdx.x; i < 1024; i += 256) w2[i] = W2[i];
  __syncthreads();
  int gid = blockIdx.x * 256 + threadIdx.x;
  int i = gid >> 5, c = gid & 31;
  if (i >= N) return;
  float acc = bf2f(hWs1[(size_t)i * 32 + c]);
  int beg = rowptr[i], end = rowptr[i + 1];
  int j = beg;
  while (j + 15 < end) {  // fast path: 16 edges, 1 coalesced idx load + shfl
    int mye = esrc[j + (c & 15)];
#pragma unroll
    for (int t = 0; t < 16; ++t) {
      int s = __shfl(mye, t, 32);
      acc += bf2f(hWs1[(size_t)s * 32 + c]);
    }
    j += 16;
  }
  for (; j < end; ++j) acc += bf2f(hWs1[(size_t)esrc[j] * 32 + c]);
  float dv = dinv[i];
  float r = fmaxf(fmaf(dv, acc, b1[c]), 0.f);
  float acc2 = 0.f;
#pragma unroll
  for (int k = 0; k < 32; ++k)
    acc2 = fmaf(__shfl(r, k, 32), w2[k * 32 + c], acc2);
  hWs2[(size_t)i * 32 + c] = f2bf(dv * acc2);
}

// layer-2 gather + fused score head (32-lane shfl reduce)
__global__ __launch_bounds__(256) void k_gather_score(
    const int* __restrict__ esrc, const int* __restrict__ rowptr,
    const float* __restrict__ dinv, const u16* __restrict__ hWs,
    const float* __restrict__ bias, const float* __restrict__ Wh,
    const float* __restrict__ bh, const float* __restrict__ cash,
    float* __restrict__ scores, int N) {
  int gid = blockIdx.x * 256 + threadIdx.x;
  if (gid == 0) scores[0] = cash[0];
  int i = gid >> 5, c = gid & 31;
  if (i >= N) return;
  float acc = bf2f(hWs[(size_t)i * 32 + c]);
  int beg = rowptr[i], end = rowptr[i + 1];
  int j = beg;
  while (j + 15 < end) {
    int mye = esrc[j + (c & 15)];
#pragma unroll
    for (int t = 0; t < 16; ++t) {
      int s = __shfl(mye, t, 32);
      acc += bf2f(hWs[(size_t)s * 32 + c]);
    }
    j += 16;
  }
  for (; j < end; ++j) acc += bf2f(hWs[(size_t)esrc[j] * 32 + c]);
  float val = fmaf(dinv[i], acc, bias[c]);
  float t = fmaxf(val, 0.f) * Wh[c];
#pragma unroll
  for (int m = 16; m >= 1; m >>= 1) t += __shfl_xor(t, m, 32);
  if (c == 0) scores[1 + i] = t + bh[0];
}

// --- online softmax: per-block (max, sumexp) partials ---
__global__ __launch_bounds__(256) void k_sm_part(const float* __restrict__ s, int n,
                                                 float2* __restrict__ part) {
  float m = -3.4e38f, sum = 0.f;
  for (int i = blockIdx.x * 256 + threadIdx.x; i < n; i += 256 * 256) {
    float x = s[i];
    if (x > m) { sum = sum * expf(m - x) + 1.f; m = x; }
    else sum += expf(x - m);
  }
  __shared__ float sm_m[256], sm_s[256];
  sm_m[threadIdx.x] = m; sm_s[threadIdx.x] = sum;
  __syncthreads();
  for (int o = 128; o > 0; o >>= 1) {
    if (threadIdx.x < o) {
      float m1 = sm_m[threadIdx.x], s1 = sm_s[threadIdx.x];
      float m2 = sm_m[threadIdx.x + o], s2 = sm_s[threadIdx.x + o];
      float M = fmaxf(m1, m2);
      sm_s[threadIdx.x] = s1 * expf(m1 - M) + s2 * expf(m2 - M);
      sm_m[threadIdx.x] = M;
    }
    __syncthreads();
  }
  if (threadIdx.x == 0) part[blockIdx.x] = make_float2(sm_m[0], sm_s[0]);
}

__global__ __launch_bounds__(256) void k_sm_fin(const float2* __restrict__ part,
                                                float* __restrict__ finals) {
  __shared__ float sm_m[256], sm_s[256];
  float2 p = part[threadIdx.x];
  sm_m[threadIdx.x] = p.x; sm_s[threadIdx.x] = p.y;
  __syncthreads();
  for (int o = 128; o > 0; o >>= 1) {
    if (threadIdx.x < o) {
      float m1 = sm_m[threadIdx.x], s1 = sm_s[threadIdx.x];
      float m2 = sm_m[threadIdx.x + o], s2 = sm_s[threadIdx.x + o];
      float M = fmaxf(m1, m2);
      sm_s[threadIdx.x] = s1 * expf(m1 - M) + s2 * expf(m2 - M);
      sm_m[threadIdx.x] = M;
    }
    __syncthreads();
  }
  if (threadIdx.x == 0) { finals[0] = sm_m[0]; finals[1] = sm_s[0]; }
}

__global__ void k_sm_out(const float* __restrict__ s, int n,
                         const float* __restrict__ finals, float* __restrict__ out) {
  int i = blockIdx.x * 256 + threadIdx.x;
  if (i < n) out[i] = expf(s[i] - finals[0]) / finals[1];
}

extern "C" void kernel_launch(void* const* d_in, const int* in_sizes, int n_in,
                              void* d_out, int out_size, void* d_ws, size_t ws_size,
                              hipStream_t stream) {
  const float* x    = (const float*)d_in[0];
  const int*   ei   = (const int*)d_in[1];
  const float* W1   = (const float*)d_in[2];
  const float* b1   = (const float*)d_in[3];
  const float* W2   = (const float*)d_in[4];
  const float* b2   = (const float*)d_in[5];
  const float* Wh   = (const float*)d_in[6];
  const float* bh   = (const float*)d_in[7];
  const float* cash = (const float*)d_in[8];

  const int N = in_sizes[0] / 128;
  const int E = in_sizes[1] / 2;
  const int* src = ei;
  const int* dst = ei + E;
  const int nbuk = cdiv(N, 512);  // 196 for N=100000 (<= NBMAX)

  char* p = (char*)d_ws;
  float* dinv   = (float*)p; p += sizeof(float) * N;
  u16*   hWs1   = (u16*)p;   p += sizeof(u16) * (size_t)N * 32;
  u16*   hWs2   = (u16*)p;   p += sizeof(u16) * (size_t)N * 32;
  float* scores = (float*)p; p += sizeof(float) * (N + 1);
  float2* part  = (float2*)p; p += sizeof(float2) * 256;
  float* finals = (float*)p; p += sizeof(float) * 4;
  unsigned* gcur  = (unsigned*)p; p += sizeof(unsigned) * NBMAX;
  unsigned* bbase = (unsigned*)p; p += sizeof(unsigned) * NBMAX;
  int* rowptr = (int*)p; p += sizeof(int) * (N + 1);
  unsigned* ebuf = (unsigned*)p; p += sizeof(unsigned) * (size_t)nbuk * CAP;
  int* esrc   = (int*)p; p += sizeof(int) * (size_t)E;
  float* out = (float*)d_out;
  const int n = N + 1;

  // --- CSR build (coarse-bucket counting sort; shared by both layers) ---
  (void)hipMemsetAsync(gcur, 0, sizeof(unsigned) * NBMAX, stream);
  k_bin<<<cdiv(E, EPB), 256, 0, stream>>>(src, dst, gcur, ebuf, E, nbuk);
  k_bukscan<<<1, 256, 0, stream>>>(gcur, bbase, rowptr, nbuk, N);
  k_place<<<nbuk, 512, 0, stream>>>(gcur, ebuf, bbase, rowptr, dinv, esrc, N);

  // --- layer 1 (+ fused layer-2 transform) ---
  k_gemm1<<<cdiv(N, 256), 256, 0, stream>>>(x, W1, dinv, hWs1, N);
  k_gather_fuse<<<cdiv((long)N * 32, 256), 256, 0, stream>>>(
      esrc, rowptr, dinv, hWs1, b1, W2, hWs2, N);

  // --- layer 2 gather + fused score head ---
  k_gather_score<<<cdiv((long)N * 32, 256), 256, 0, stream>>>(
      esrc, rowptr, dinv, hWs2, b2, Wh, bh, cash, scores, N);

  // --- online softmax (3 kernels) ---
  k_sm_part<<<256, 256, 0, stream>>>(scores, n, part);
  k_sm_fin<<<1, 256, 0, stream>>>(part, finals);
  k_sm_out<<<cdiv(n, 256), 256, 0, stream>>>(scores, n, finals, out);
}

// Round 14
// 251.179 us; speedup vs baseline: 1.2408x; 1.2408x over previous
//
#include <hip/hip_runtime.h>
#include <math.h>

// GCN forward: coarse-bucket counting-sort CSR + node-parallel bf16 gather.
// Measured models (R4-R13):
//   - device-scope atomic ~= 35B fabric + ~41ns, invariant to locality ->
//     minimize atomic COUNT (k_bin: 1 reservation per block-bucket).
//   - k_bin traffic = fragment count -> coarse buckets (196 x 512 nodes).
//   - gather must be node-parallel; bf16 rows = 64B/edge.
//   - gemm1 must be row-per-thread (R13: 72.8 -> <15us; lane streams own row,
//     W1 LDS-broadcast; broadcast-x layout wasted 32B/instr).
//   - R13 FAILURE: shfl-distributed esrc indices serialize row loads (each
//     load waits on a VALU shfl) + VGPR 40 dropped occupancy. Direct
//     broadcast esrc loads + 8 independent row loads in flight win (R12).
// Pipeline: k_bin -> k_bukscan -> k_place -> k_gemm1 (row/thread) ->
//   k_gather_fuse (layer1 gather + ReLU + W2 via shfl, writes hWs2 bf16) ->
//   k_gather_score (layer2 gather + score head) -> 3-kernel online softmax.

static inline int cdiv(long a, int b) { return (int)((a + (long)b - 1) / b); }

#define EPB 8192      // edges per k_bin block (391 blocks @ E=3.2M)
#define NBMAX 256     // max buckets (N <= 131072 @ 512 nodes/bucket)
#define CAP 17408     // per-bucket capacity; mean 16384, +8 sigma

typedef unsigned short u16;
typedef int iv4 __attribute__((ext_vector_type(4)));

__device__ __forceinline__ u16 f2bf(float f) {  // RNE f32->bf16
  unsigned u = __float_as_uint(f);
  return (u16)((u + 0x7FFFu + ((u >> 16) & 1u)) >> 16);
}
__device__ __forceinline__ float bf2f(u16 h) {
  return __uint_as_float(((unsigned)h) << 16);
}

// --- binning: LDS hist -> one reservation atomic per (block,bucket) -> fill runs
__global__ __launch_bounds__(256) void k_bin(const int* __restrict__ src,
                                             const int* __restrict__ dst,
                                             unsigned* __restrict__ gcur,
                                             unsigned* __restrict__ ebuf,
                                             int E, int nbuk) {
  __shared__ unsigned lhist[NBMAX];
  __shared__ unsigned lcur[NBMAX];
  int tid = threadIdx.x;
  for (int i = tid; i < nbuk; i += 256) lhist[i] = 0;
  __syncthreads();
  int e0 = blockIdx.x * EPB, e1 = min(e0 + EPB, E);
  int nvec = (e1 - e0) >> 10;  // 1024-edge chunks (256 thr x 4)
  for (int k = 0; k < nvec; ++k) {
    iv4 d4 = __builtin_nontemporal_load((const iv4*)(dst + e0 + (k << 10) + tid * 4));
    atomicAdd(&lhist[d4.x >> 9], 1u);
    atomicAdd(&lhist[d4.y >> 9], 1u);
    atomicAdd(&lhist[d4.z >> 9], 1u);
    atomicAdd(&lhist[d4.w >> 9], 1u);
  }
  for (int e = e0 + (nvec << 10) + tid; e < e1; e += 256)
    atomicAdd(&lhist[__builtin_nontemporal_load(&dst[e]) >> 9], 1u);
  __syncthreads();
  for (int b = tid; b < nbuk; b += 256) {
    unsigned nn = lhist[b];
    lcur[b] = nn ? atomicAdd(&gcur[b], nn) : 0u;  // run reservation
  }
  __syncthreads();
  for (int k = 0; k < nvec; ++k) {
    int base = e0 + (k << 10) + tid * 4;
    iv4 d4 = __builtin_nontemporal_load((const iv4*)(dst + base));
    iv4 s4 = __builtin_nontemporal_load((const iv4*)(src + base));
#define PUT(dd, ss)                                              \
    {                                                            \
      int bb = (dd) >> 9;                                        \
      unsigned off = atomicAdd(&lcur[bb], 1u);                   \
      if (off < CAP)                                             \
        ebuf[(size_t)bb * CAP + off] =                           \
            ((unsigned)((dd) & 511) << 17) | (unsigned)(ss);     \
    }
    PUT(d4.x, s4.x) PUT(d4.y, s4.y) PUT(d4.z, s4.z) PUT(d4.w, s4.w)
  }
  for (int e = e0 + (nvec << 10) + tid; e < e1; e += 256) {
    int d = __builtin_nontemporal_load(&dst[e]);
    int s = __builtin_nontemporal_load(&src[e]);
    PUT(d, s)
  }
#undef PUT
}

// --- exclusive scan of bucket counts (one block; nbuk <= 256)
__global__ __launch_bounds__(256) void k_bukscan(const unsigned* __restrict__ gcur,
                                                 unsigned* __restrict__ bbase,
                                                 int* __restrict__ rowptr,
                                                 int nbuk, int N) {
  __shared__ unsigned sm[256];
  int t = threadIdx.x;
  unsigned v = (t < nbuk) ? min(gcur[t], (unsigned)CAP) : 0u;
  sm[t] = v;
  __syncthreads();
  for (int o = 1; o < 256; o <<= 1) {
    unsigned add = (t >= o) ? sm[t - o] : 0u;
    __syncthreads();
    sm[t] += add;
    __syncthreads();
  }
  if (t < nbuk) bbase[t] = sm[t] - v;  // exclusive
  if (t == 255) rowptr[N] = (int)sm[255];
}

// --- per-bucket (512 nodes): LDS count+scan -> rowptr/dinv; sort run into esrc.
__global__ __launch_bounds__(512) void k_place(const unsigned* __restrict__ gcur,
                                               const unsigned* __restrict__ ebuf,
                                               const unsigned* __restrict__ bbase,
                                               int* __restrict__ rowptr,
                                               float* __restrict__ dinv,
                                               int* __restrict__ esrc, int N) {
  __shared__ unsigned lcnt[512];
  __shared__ unsigned lofs[512];
  int b = blockIdx.x, tid = threadIdx.x;
  lcnt[tid] = 0;
  __syncthreads();
  int cnt = min((int)gcur[b], CAP);
  const unsigned* eb = ebuf + (size_t)b * CAP;
  for (int j = tid; j < cnt; j += 512) atomicAdd(&lcnt[eb[j] >> 17], 1u);
  __syncthreads();
  unsigned myc = lcnt[tid];
  lofs[tid] = myc;
  __syncthreads();
  for (int o = 1; o < 512; o <<= 1) {  // inclusive scan over 512
    unsigned add = (tid >= o) ? lofs[tid - o] : 0u;
    __syncthreads();
    lofs[tid] += add;
    __syncthreads();
  }
  unsigned base = bbase[b];
  unsigned ex = lofs[tid] - myc;  // exclusive (own entry only)
  int node = (b << 9) + tid;
  if (node < N) {
    rowptr[node] = (int)(base + ex);
    dinv[node] = rsqrtf((float)myc + 1.0f);  // deg = cnt + self-loop
  }
  lofs[tid] = ex;  // reuse as cursor
  __syncthreads();
  for (int j = tid; j < cnt; j += 512) {
    unsigned p = eb[j];
    unsigned r = atomicAdd(&lofs[p >> 17], 1u);  // LDS atomic
    esrc[base + r] = (int)(p & 0x1FFFF);
  }
}

// hWs = bf16(dinv[r] * (x @ W1)); ONE THREAD PER ROW, 32 accumulators.
__global__ __launch_bounds__(256) void k_gemm1(
    const float* __restrict__ x, const float* __restrict__ W1,
    const float* __restrict__ dinv, u16* __restrict__ hWs, int N) {
  __shared__ float4 w[128 * 8];  // w[k][q] = W1[k][4q..4q+3]
  for (int i = threadIdx.x; i < 1024; i += 256) w[i] = ((const float4*)W1)[i];
  __syncthreads();
  int r = blockIdx.x * 256 + threadIdx.x;
  if (r >= N) return;
  const float4* xr = (const float4*)(x + (size_t)r * 128);
  float acc[32];
#pragma unroll
  for (int c = 0; c < 32; ++c) acc[c] = 0.f;
  for (int k4 = 0; k4 < 32; ++k4) {
    float4 xv = xr[k4];
#pragma unroll
    for (int kk = 0; kk < 4; ++kk) {
      float xk = (kk == 0) ? xv.x : (kk == 1) ? xv.y : (kk == 2) ? xv.z : xv.w;
      const float4* wk = &w[(k4 * 4 + kk) * 8];
#pragma unroll
      for (int q = 0; q < 8; ++q) {
        float4 wv = wk[q];
        acc[q * 4 + 0] = fmaf(xk, wv.x, acc[q * 4 + 0]);
        acc[q * 4 + 1] = fmaf(xk, wv.y, acc[q * 4 + 1]);
        acc[q * 4 + 2] = fmaf(xk, wv.z, acc[q * 4 + 2]);
        acc[q * 4 + 3] = fmaf(xk, wv.w, acc[q * 4 + 3]);
      }
    }
  }
  float dv = dinv[r];
  unsigned pk[16];
#pragma unroll
  for (int q = 0; q < 16; ++q) {
    unsigned lo = f2bf(dv * acc[2 * q]);
    unsigned hi = f2bf(dv * acc[2 * q + 1]);
    pk[q] = lo | (hi << 16);
  }
  uint4* o4 = (uint4*)(hWs + (size_t)r * 32);
  o4[0] = make_uint4(pk[0], pk[1], pk[2], pk[3]);
  o4[1] = make_uint4(pk[4], pk[5], pk[6], pk[7]);
  o4[2] = make_uint4(pk[8], pk[9], pk[10], pk[11]);
  o4[3] = make_uint4(pk[12], pk[13], pk[14], pk[15]);
}

// layer-1 gather fused with layer-2 transform. 32 lanes/node, lane = column.
// Direct (broadcast) esrc loads + 8 independent row loads in flight (R12 form).
//   r_c = relu(b1[c] + dinv_i*(hWs1[i,c] + sum_s hWs1[s,c]))
//   hWs2[i,c] = bf16(dinv_i * sum_k r_k * W2[k,c])
__global__ __launch_bounds__(256) void k_gather_fuse(
    const int* __restrict__ esrc, const int* __restrict__ rowptr,
    const float* __restrict__ dinv, const u16* __restrict__ hWs1,
    const float* __restrict__ b1, const float* __restrict__ W2,
    u16* __restrict__ hWs2, int N) {
  __shared__ float w2[32 * 32];
  for (int i = threadIdx.x; i < 1024; i += 256) w2[i] = W2[i];
  __syncthreads();
  int gid = blockIdx.x * 256 + threadIdx.x;
  int i = gid >> 5, c = gid & 31;
  if (i >= N) return;
  float acc = bf2f(hWs1[(size_t)i * 32 + c]);
  int beg = rowptr[i], end = rowptr[i + 1];
  int j = beg;
  for (; j + 7 < end; j += 8) {
    float v0 = bf2f(hWs1[(size_t)esrc[j + 0] * 32 + c]);
    float v1 = bf2f(hWs1[(size_t)esrc[j + 1] * 32 + c]);
    float v2 = bf2f(hWs1[(size_t)esrc[j + 2] * 32 + c]);
    float v3 = bf2f(hWs1[(size_t)esrc[j + 3] * 32 + c]);
    float v4 = bf2f(hWs1[(size_t)esrc[j + 4] * 32 + c]);
    float v5 = bf2f(hWs1[(size_t)esrc[j + 5] * 32 + c]);
    float v6 = bf2f(hWs1[(size_t)esrc[j + 6] * 32 + c]);
    float v7 = bf2f(hWs1[(size_t)esrc[j + 7] * 32 + c]);
    acc += ((v0 + v1) + (v2 + v3)) + ((v4 + v5) + (v6 + v7));
  }
  for (; j < end; ++j) acc += bf2f(hWs1[(size_t)esrc[j] * 32 + c]);
  float dv = dinv[i];
  float r = fmaxf(fmaf(dv, acc, b1[c]), 0.f);
  float acc2 = 0.f;
#pragma unroll
  for (int k = 0; k < 32; ++k)
    acc2 = fmaf(__shfl(r, k, 32), w2[k * 32 + c], acc2);
  hWs2[(size_t)i * 32 + c] = f2bf(dv * acc2);
}

// layer-2 gather + fused score head (32-lane shfl reduce)
__global__ __launch_bounds__(256) void k_gather_score(
    const int* __restrict__ esrc, const int* __restrict__ rowptr,
    const float* __restrict__ dinv, const u16* __restrict__ hWs,
    const float* __restrict__ bias, const float* __restrict__ Wh,
    const float* __restrict__ bh, const float* __restrict__ cash,
    float* __restrict__ scores, int N) {
  int gid = blockIdx.x * 256 + threadIdx.x;
  if (gid == 0) scores[0] = cash[0];
  int i = gid >> 5, c = gid & 31;
  if (i >= N) return;
  float acc = bf2f(hWs[(size_t)i * 32 + c]);
  int beg = rowptr[i], end = rowptr[i + 1];
  int j = beg;
  for (; j + 7 < end; j += 8) {
    float v0 = bf2f(hWs[(size_t)esrc[j + 0] * 32 + c]);
    float v1 = bf2f(hWs[(size_t)esrc[j + 1] * 32 + c]);
    float v2 = bf2f(hWs[(size_t)esrc[j + 2] * 32 + c]);
    float v3 = bf2f(hWs[(size_t)esrc[j + 3] * 32 + c]);
    float v4 = bf2f(hWs[(size_t)esrc[j + 4] * 32 + c]);
    float v5 = bf2f(hWs[(size_t)esrc[j + 5] * 32 + c]);
    float v6 = bf2f(hWs[(size_t)esrc[j + 6] * 32 + c]);
    float v7 = bf2f(hWs[(size_t)esrc[j + 7] * 32 + c]);
    acc += ((v0 + v1) + (v2 + v3)) + ((v4 + v5) + (v6 + v7));
  }
  for (; j < end; ++j) acc += bf2f(hWs[(size_t)esrc[j] * 32 + c]);
  float val = fmaf(dinv[i], acc, bias[c]);
  float t = fmaxf(val, 0.f) * Wh[c];
#pragma unroll
  for (int m = 16; m >= 1; m >>= 1) t += __shfl_xor(t, m, 32);
  if (c == 0) scores[1 + i] = t + bh[0];
}

// --- online softmax: per-block (max, sumexp) partials ---
__global__ __launch_bounds__(256) void k_sm_part(const float* __restrict__ s, int n,
                                                 float2* __restrict__ part) {
  float m = -3.4e38f, sum = 0.f;
  for (int i = blockIdx.x * 256 + threadIdx.x; i < n; i += 256 * 256) {
    float x = s[i];
    if (x > m) { sum = sum * expf(m - x) + 1.f; m = x; }
    else sum += expf(x - m);
  }
  __shared__ float sm_m[256], sm_s[256];
  sm_m[threadIdx.x] = m; sm_s[threadIdx.x] = sum;
  __syncthreads();
  for (int o = 128; o > 0; o >>= 1) {
    if (threadIdx.x < o) {
      float m1 = sm_m[threadIdx.x], s1 = sm_s[threadIdx.x];
      float m2 = sm_m[threadIdx.x + o], s2 = sm_s[threadIdx.x + o];
      float M = fmaxf(m1, m2);
      sm_s[threadIdx.x] = s1 * expf(m1 - M) + s2 * expf(m2 - M);
      sm_m[threadIdx.x] = M;
    }
    __syncthreads();
  }
  if (threadIdx.x == 0) part[blockIdx.x] = make_float2(sm_m[0], sm_s[0]);
}

__global__ __launch_bounds__(256) void k_sm_fin(const float2* __restrict__ part,
                                                float* __restrict__ finals) {
  __shared__ float sm_m[256], sm_s[256];
  float2 p = part[threadIdx.x];
  sm_m[threadIdx.x] = p.x; sm_s[threadIdx.x] = p.y;
  __syncthreads();
  for (int o = 128; o > 0; o >>= 1) {
    if (threadIdx.x < o) {
      float m1 = sm_m[threadIdx.x], s1 = sm_s[threadIdx.x];
      float m2 = sm_m[threadIdx.x + o], s2 = sm_s[threadIdx.x + o];
      float M = fmaxf(m1, m2);
      sm_s[threadIdx.x] = s1 * expf(m1 - M) + s2 * expf(m2 - M);
      sm_m[threadIdx.x] = M;
    }
    __syncthreads();
  }
  if (threadIdx.x == 0) { finals[0] = sm_m[0]; finals[1] = sm_s[0]; }
}

__global__ void k_sm_out(const float* __restrict__ s, int n,
                         const float* __restrict__ finals, float* __restrict__ out) {
  int i = blockIdx.x * 256 + threadIdx.x;
  if (i < n) out[i] = expf(s[i] - finals[0]) / finals[1];
}

extern "C" void kernel_launch(void* const* d_in, const int* in_sizes, int n_in,
                              void* d_out, int out_size, void* d_ws, size_t ws_size,
                              hipStream_t stream) {
  const float* x    = (const float*)d_in[0];
  const int*   ei   = (const int*)d_in[1];
  const float* W1   = (const float*)d_in[2];
  const float* b1   = (const float*)d_in[3];
  const float* W2   = (const float*)d_in[4];
  const float* b2   = (const float*)d_in[5];
  const float* Wh   = (const float*)d_in[6];
  const float* bh   = (const float*)d_in[7];
  const float* cash = (const float*)d_in[8];

  const int N = in_sizes[0] / 128;
  const int E = in_sizes[1] / 2;
  const int* src = ei;
  const int* dst = ei + E;
  const int nbuk = cdiv(N, 512);  // 196 for N=100000 (<= NBMAX)

  char* p = (char*)d_ws;
  float* dinv   = (float*)p; p += sizeof(float) * N;
  u16*   hWs1   = (u16*)p;   p += sizeof(u16) * (size_t)N * 32;
  u16*   hWs2   = (u16*)p;   p += sizeof(u16) * (size_t)N * 32;
  float* scores = (float*)p; p += sizeof(float) * (N + 1);
  float2* part  = (float2*)p; p += sizeof(float2) * 256;
  float* finals = (float*)p; p += sizeof(float) * 4;
  unsigned* gcur  = (unsigned*)p; p += sizeof(unsigned) * NBMAX;
  unsigned* bbase = (unsigned*)p; p += sizeof(unsigned) * NBMAX;
  int* rowptr = (int*)p; p += sizeof(int) * (N + 1);
  unsigned* ebuf = (unsigned*)p; p += sizeof(unsigned) * (size_t)nbuk * CAP;
  int* esrc   = (int*)p; p += sizeof(int) * (size_t)E;
  float* out = (float*)d_out;
  const int n = N + 1;

  // --- CSR build (coarse-bucket counting sort; shared by both layers) ---
  (void)hipMemsetAsync(gcur, 0, sizeof(unsigned) * NBMAX, stream);
  k_bin<<<cdiv(E, EPB), 256, 0, stream>>>(src, dst, gcur, ebuf, E, nbuk);
  k_bukscan<<<1, 256, 0, stream>>>(gcur, bbase, rowptr, nbuk, N);
  k_place<<<nbuk, 512, 0, stream>>>(gcur, ebuf, bbase, rowptr, dinv, esrc, N);

  // --- layer 1 (+ fused layer-2 transform) ---
  k_gemm1<<<cdiv(N, 256), 256, 0, stream>>>(x, W1, dinv, hWs1, N);
  k_gather_fuse<<<cdiv((long)N * 32, 256), 256, 0, stream>>>(
      esrc, rowptr, dinv, hWs1, b1, W2, hWs2, N);

  // --- layer 2 gather + fused score head ---
  k_gather_score<<<cdiv((long)N * 32, 256), 256, 0, stream>>>(
      esrc, rowptr, dinv, hWs2, b2, Wh, bh, cash, scores, N);

  // --- online softmax (3 kernels) ---
  k_sm_part<<<256, 256, 0, stream>>>(scores, n, part);
  k_sm_fin<<<1, 256, 0, stream>>>(part, finals);
  k_sm_out<<<cdiv(n, 256), 256, 0, stream>>>(scores, n, finals, out);
}

// Round 15
// 208.537 us; speedup vs baseline: 1.4945x; 1.2045x over previous
//
#include <hip/hip_runtime.h>
#include <math.h>

// GCN forward: coarse-bucket counting-sort CSR + node-parallel bf16 gather.
// Measured models (R4-R14):
//   - device-scope atomic ~= 35B fabric + ~41ns -> minimize atomic COUNT.
//   - k_bin traffic = fragment count -> coarse buckets (196 x 512 nodes).
//   - gemm1 row-per-thread (lane streams own row; broadcast-x wasted 32B/instr).
//   - R13: shfl-distributed esrc serializes row loads -> keep broadcast esrc.
//   - R9 vs R12: f32->bf16 rows did NOT speed gather => gathers are
//     instruction/request-count bound, not byte bound. THIS ROUND: 8 lanes per
//     node, uint2 (4 cols) per lane -> 4x fewer vmem instrs, ~2x less VALU,
//     4x more loads in flight. Same 64B line per edge.
// Pipeline: k_bin -> k_bukscan -> k_place -> k_gemm1 -> k_gather_fuse
//   (layer1 gather + ReLU + W2, writes hWs2 bf16) -> k_gather_score
//   (layer2 gather + score head) -> 3-kernel online softmax.

static inline int cdiv(long a, int b) { return (int)((a + (long)b - 1) / b); }

#define EPB 8192      // edges per k_bin block (391 blocks @ E=3.2M)
#define NBMAX 256     // max buckets (N <= 131072 @ 512 nodes/bucket)
#define CAP 17408     // per-bucket capacity; mean 16384, +8 sigma

typedef unsigned short u16;
typedef int iv4 __attribute__((ext_vector_type(4)));

__device__ __forceinline__ u16 f2bf(float f) {  // RNE f32->bf16
  unsigned u = __float_as_uint(f);
  return (u16)((u + 0x7FFFu + ((u >> 16) & 1u)) >> 16);
}
__device__ __forceinline__ float lo16f(unsigned v) {
  return __uint_as_float(v << 16);
}
__device__ __forceinline__ float hi16f(unsigned v) {
  return __uint_as_float(v & 0xFFFF0000u);
}

// --- binning: LDS hist -> one reservation atomic per (block,bucket) -> fill runs
__global__ __launch_bounds__(256) void k_bin(const int* __restrict__ src,
                                             const int* __restrict__ dst,
                                             unsigned* __restrict__ gcur,
                                             unsigned* __restrict__ ebuf,
                                             int E, int nbuk) {
  __shared__ unsigned lhist[NBMAX];
  __shared__ unsigned lcur[NBMAX];
  int tid = threadIdx.x;
  for (int i = tid; i < nbuk; i += 256) lhist[i] = 0;
  __syncthreads();
  int e0 = blockIdx.x * EPB, e1 = min(e0 + EPB, E);
  int nvec = (e1 - e0) >> 10;  // 1024-edge chunks (256 thr x 4)
  for (int k = 0; k < nvec; ++k) {
    iv4 d4 = __builtin_nontemporal_load((const iv4*)(dst + e0 + (k << 10) + tid * 4));
    atomicAdd(&lhist[d4.x >> 9], 1u);
    atomicAdd(&lhist[d4.y >> 9], 1u);
    atomicAdd(&lhist[d4.z >> 9], 1u);
    atomicAdd(&lhist[d4.w >> 9], 1u);
  }
  for (int e = e0 + (nvec << 10) + tid; e < e1; e += 256)
    atomicAdd(&lhist[__builtin_nontemporal_load(&dst[e]) >> 9], 1u);
  __syncthreads();
  for (int b = tid; b < nbuk; b += 256) {
    unsigned nn = lhist[b];
    lcur[b] = nn ? atomicAdd(&gcur[b], nn) : 0u;  // run reservation
  }
  __syncthreads();
  for (int k = 0; k < nvec; ++k) {
    int base = e0 + (k << 10) + tid * 4;
    iv4 d4 = __builtin_nontemporal_load((const iv4*)(dst + base));
    iv4 s4 = __builtin_nontemporal_load((const iv4*)(src + base));
#define PUT(dd, ss)                                              \
    {                                                            \
      int bb = (dd) >> 9;                                        \
      unsigned off = atomicAdd(&lcur[bb], 1u);                   \
      if (off < CAP)                                             \
        ebuf[(size_t)bb * CAP + off] =                           \
            ((unsigned)((dd) & 511) << 17) | (unsigned)(ss);     \
    }
    PUT(d4.x, s4.x) PUT(d4.y, s4.y) PUT(d4.z, s4.z) PUT(d4.w, s4.w)
  }
  for (int e = e0 + (nvec << 10) + tid; e < e1; e += 256) {
    int d = __builtin_nontemporal_load(&dst[e]);
    int s = __builtin_nontemporal_load(&src[e]);
    PUT(d, s)
  }
#undef PUT
}

// --- exclusive scan of bucket counts (one block; nbuk <= 256)
__global__ __launch_bounds__(256) void k_bukscan(const unsigned* __restrict__ gcur,
                                                 unsigned* __restrict__ bbase,
                                                 int* __restrict__ rowptr,
                                                 int nbuk, int N) {
  __shared__ unsigned sm[256];
  int t = threadIdx.x;
  unsigned v = (t < nbuk) ? min(gcur[t], (unsigned)CAP) : 0u;
  sm[t] = v;
  __syncthreads();
  for (int o = 1; o < 256; o <<= 1) {
    unsigned add = (t >= o) ? sm[t - o] : 0u;
    __syncthreads();
    sm[t] += add;
    __syncthreads();
  }
  if (t < nbuk) bbase[t] = sm[t] - v;  // exclusive
  if (t == 255) rowptr[N] = (int)sm[255];
}

// --- per-bucket (512 nodes): LDS count+scan -> rowptr/dinv; sort run into esrc.
__global__ __launch_bounds__(512) void k_place(const unsigned* __restrict__ gcur,
                                               const unsigned* __restrict__ ebuf,
                                               const unsigned* __restrict__ bbase,
                                               int* __restrict__ rowptr,
                                               float* __restrict__ dinv,
                                               int* __restrict__ esrc, int N) {
  __shared__ unsigned lcnt[512];
  __shared__ unsigned lofs[512];
  int b = blockIdx.x, tid = threadIdx.x;
  lcnt[tid] = 0;
  __syncthreads();
  int cnt = min((int)gcur[b], CAP);
  const unsigned* eb = ebuf + (size_t)b * CAP;
  for (int j = tid; j < cnt; j += 512) atomicAdd(&lcnt[eb[j] >> 17], 1u);
  __syncthreads();
  unsigned myc = lcnt[tid];
  lofs[tid] = myc;
  __syncthreads();
  for (int o = 1; o < 512; o <<= 1) {  // inclusive scan over 512
    unsigned add = (tid >= o) ? lofs[tid - o] : 0u;
    __syncthreads();
    lofs[tid] += add;
    __syncthreads();
  }
  unsigned base = bbase[b];
  unsigned ex = lofs[tid] - myc;  // exclusive (own entry only)
  int node = (b << 9) + tid;
  if (node < N) {
    rowptr[node] = (int)(base + ex);
    dinv[node] = rsqrtf((float)myc + 1.0f);  // deg = cnt + self-loop
  }
  lofs[tid] = ex;  // reuse as cursor
  __syncthreads();
  for (int j = tid; j < cnt; j += 512) {
    unsigned p = eb[j];
    unsigned r = atomicAdd(&lofs[p >> 17], 1u);  // LDS atomic
    esrc[base + r] = (int)(p & 0x1FFFF);
  }
}

// hWs = bf16(dinv[r] * (x @ W1)); ONE THREAD PER ROW, 32 accumulators.
__global__ __launch_bounds__(256) void k_gemm1(
    const float* __restrict__ x, const float* __restrict__ W1,
    const float* __restrict__ dinv, u16* __restrict__ hWs, int N) {
  __shared__ float4 w[128 * 8];  // w[k][q] = W1[k][4q..4q+3]
  for (int i = threadIdx.x; i < 1024; i += 256) w[i] = ((const float4*)W1)[i];
  __syncthreads();
  int r = blockIdx.x * 256 + threadIdx.x;
  if (r >= N) return;
  const float4* xr = (const float4*)(x + (size_t)r * 128);
  float acc[32];
#pragma unroll
  for (int c = 0; c < 32; ++c) acc[c] = 0.f;
  for (int k4 = 0; k4 < 32; ++k4) {
    float4 xv = xr[k4];
#pragma unroll
    for (int kk = 0; kk < 4; ++kk) {
      float xk = (kk == 0) ? xv.x : (kk == 1) ? xv.y : (kk == 2) ? xv.z : xv.w;
      const float4* wk = &w[(k4 * 4 + kk) * 8];
#pragma unroll
      for (int q = 0; q < 8; ++q) {
        float4 wv = wk[q];
        acc[q * 4 + 0] = fmaf(xk, wv.x, acc[q * 4 + 0]);
        acc[q * 4 + 1] = fmaf(xk, wv.y, acc[q * 4 + 1]);
        acc[q * 4 + 2] = fmaf(xk, wv.z, acc[q * 4 + 2]);
        acc[q * 4 + 3] = fmaf(xk, wv.w, acc[q * 4 + 3]);
      }
    }
  }
  float dv = dinv[r];
  unsigned pk[16];
#pragma unroll
  for (int q = 0; q < 16; ++q) {
    unsigned lo = f2bf(dv * acc[2 * q]);
    unsigned hi = f2bf(dv * acc[2 * q + 1]);
    pk[q] = lo | (hi << 16);
  }
  uint4* o4 = (uint4*)(hWs + (size_t)r * 32);
  o4[0] = make_uint4(pk[0], pk[1], pk[2], pk[3]);
  o4[1] = make_uint4(pk[4], pk[5], pk[6], pk[7]);
  o4[2] = make_uint4(pk[8], pk[9], pk[10], pk[11]);
  o4[3] = make_uint4(pk[12], pk[13], pk[14], pk[15]);
}

// accumulate 4 bf16 columns from packed uint2
#define ACC4(A, U)                \
  {                               \
    A.x += lo16f((U).x);          \
    A.y += hi16f((U).x);          \
    A.z += lo16f((U).y);          \
    A.w += hi16f((U).y);          \
  }

// layer-1 gather fused with layer-2 transform. 8 lanes/node, lane = 4 columns
// (uint2 = 4 bf16). Broadcast esrc loads; 8 independent uint2 row loads in flight.
//   r_q = relu(b1[q] + dinv_i*(hWs1[i,q] + sum_s hWs1[s,q]))   (q = 4 cols/lane)
//   hWs2[i,c] = bf16(dinv_i * sum_k r_k * W2[k,c])
__global__ __launch_bounds__(256) void k_gather_fuse(
    const int* __restrict__ esrc, const int* __restrict__ rowptr,
    const float* __restrict__ dinv, const uint2* __restrict__ hWs1,
    const float* __restrict__ b1, const float* __restrict__ W2,
    uint2* __restrict__ hWs2, int N) {
  __shared__ float4 w2[32 * 8];  // w2[k][q] = W2[k][4q..4q+3]
  w2[threadIdx.x] = ((const float4*)W2)[threadIdx.x];
  __syncthreads();
  int gid = blockIdx.x * 256 + threadIdx.x;
  int i = gid >> 3, c = gid & 7;
  if (i >= N) return;
  uint2 v = hWs1[(size_t)i * 8 + c];
  float4 acc = make_float4(lo16f(v.x), hi16f(v.x), lo16f(v.y), hi16f(v.y));
  int beg = rowptr[i], end = rowptr[i + 1];
  int j = beg;
  for (; j + 7 < end; j += 8) {
    int s0 = esrc[j + 0], s1 = esrc[j + 1], s2 = esrc[j + 2], s3 = esrc[j + 3];
    int s4 = esrc[j + 4], s5 = esrc[j + 5], s6 = esrc[j + 6], s7 = esrc[j + 7];
    uint2 u0 = hWs1[(size_t)s0 * 8 + c];
    uint2 u1 = hWs1[(size_t)s1 * 8 + c];
    uint2 u2 = hWs1[(size_t)s2 * 8 + c];
    uint2 u3 = hWs1[(size_t)s3 * 8 + c];
    uint2 u4 = hWs1[(size_t)s4 * 8 + c];
    uint2 u5 = hWs1[(size_t)s5 * 8 + c];
    uint2 u6 = hWs1[(size_t)s6 * 8 + c];
    uint2 u7 = hWs1[(size_t)s7 * 8 + c];
    ACC4(acc, u0) ACC4(acc, u1) ACC4(acc, u2) ACC4(acc, u3)
    ACC4(acc, u4) ACC4(acc, u5) ACC4(acc, u6) ACC4(acc, u7)
  }
  for (; j < end; ++j) {
    uint2 u = hWs1[(size_t)esrc[j] * 8 + c];
    ACC4(acc, u)
  }
  float dv = dinv[i];
  float4 bv = ((const float4*)b1)[c];
  float4 r4;
  r4.x = fmaxf(fmaf(dv, acc.x, bv.x), 0.f);
  r4.y = fmaxf(fmaf(dv, acc.y, bv.y), 0.f);
  r4.z = fmaxf(fmaf(dv, acc.z, bv.z), 0.f);
  r4.w = fmaxf(fmaf(dv, acc.w, bv.w), 0.f);
  float4 a2 = make_float4(0.f, 0.f, 0.f, 0.f);
#pragma unroll
  for (int k8 = 0; k8 < 8; ++k8) {
    float4 rr;
    rr.x = __shfl(r4.x, k8, 8);
    rr.y = __shfl(r4.y, k8, 8);
    rr.z = __shfl(r4.z, k8, 8);
    rr.w = __shfl(r4.w, k8, 8);
    float4 wv;
    wv = w2[(4 * k8 + 0) * 8 + c];
    a2.x = fmaf(rr.x, wv.x, a2.x); a2.y = fmaf(rr.x, wv.y, a2.y);
    a2.z = fmaf(rr.x, wv.z, a2.z); a2.w = fmaf(rr.x, wv.w, a2.w);
    wv = w2[(4 * k8 + 1) * 8 + c];
    a2.x = fmaf(rr.y, wv.x, a2.x); a2.y = fmaf(rr.y, wv.y, a2.y);
    a2.z = fmaf(rr.y, wv.z, a2.z); a2.w = fmaf(rr.y, wv.w, a2.w);
    wv = w2[(4 * k8 + 2) * 8 + c];
    a2.x = fmaf(rr.z, wv.x, a2.x); a2.y = fmaf(rr.z, wv.y, a2.y);
    a2.z = fmaf(rr.z, wv.z, a2.z); a2.w = fmaf(rr.z, wv.w, a2.w);
    wv = w2[(4 * k8 + 3) * 8 + c];
    a2.x = fmaf(rr.w, wv.x, a2.x); a2.y = fmaf(rr.w, wv.y, a2.y);
    a2.z = fmaf(rr.w, wv.z, a2.z); a2.w = fmaf(rr.w, wv.w, a2.w);
  }
  uint2 o;
  o.x = (unsigned)f2bf(dv * a2.x) | ((unsigned)f2bf(dv * a2.y) << 16);
  o.y = (unsigned)f2bf(dv * a2.z) | ((unsigned)f2bf(dv * a2.w) << 16);
  hWs2[(size_t)i * 8 + c] = o;
}

// layer-2 gather + fused score head. 8 lanes/node, 4 cols/lane.
__global__ __launch_bounds__(256) void k_gather_score(
    const int* __restrict__ esrc, const int* __restrict__ rowptr,
    const float* __restrict__ dinv, const uint2* __restrict__ hWs,
    const float* __restrict__ bias, const float* __restrict__ Wh,
    const float* __restrict__ bh, const float* __restrict__ cash,
    float* __restrict__ scores, int N) {
  int gid = blockIdx.x * 256 + threadIdx.x;
  if (gid == 0) scores[0] = cash[0];
  int i = gid >> 3, c = gid & 7;
  if (i >= N) return;
  uint2 v = hWs[(size_t)i * 8 + c];
  float4 acc = make_float4(lo16f(v.x), hi16f(v.x), lo16f(v.y), hi16f(v.y));
  int beg = rowptr[i], end = rowptr[i + 1];
  int j = beg;
  for (; j + 7 < end; j += 8) {
    int s0 = esrc[j + 0], s1 = esrc[j + 1], s2 = esrc[j + 2], s3 = esrc[j + 3];
    int s4 = esrc[j + 4], s5 = esrc[j + 5], s6 = esrc[j + 6], s7 = esrc[j + 7];
    uint2 u0 = hWs[(size_t)s0 * 8 + c];
    uint2 u1 = hWs[(size_t)s1 * 8 + c];
    uint2 u2 = hWs[(size_t)s2 * 8 + c];
    uint2 u3 = hWs[(size_t)s3 * 8 + c];
    uint2 u4 = hWs[(size_t)s4 * 8 + c];
    uint2 u5 = hWs[(size_t)s5 * 8 + c];
    uint2 u6 = hWs[(size_t)s6 * 8 + c];
    uint2 u7 = hWs[(size_t)s7 * 8 + c];
    ACC4(acc, u0) ACC4(acc, u1) ACC4(acc, u2) ACC4(acc, u3)
    ACC4(acc, u4) ACC4(acc, u5) ACC4(acc, u6) ACC4(acc, u7)
  }
  for (; j < end; ++j) {
    uint2 u = hWs[(size_t)esrc[j] * 8 + c];
    ACC4(acc, u)
  }
  float dv = dinv[i];
  float4 bv = ((const float4*)bias)[c];
  float4 wh = ((const float4*)Wh)[c];
  float t = fmaxf(fmaf(dv, acc.x, bv.x), 0.f) * wh.x +
            fmaxf(fmaf(dv, acc.y, bv.y), 0.f) * wh.y +
            fmaxf(fmaf(dv, acc.z, bv.z), 0.f) * wh.z +
            fmaxf(fmaf(dv, acc.w, bv.w), 0.f) * wh.w;
#pragma unroll
  for (int m = 4; m >= 1; m >>= 1) t += __shfl_xor(t, m, 8);
  if (c == 0) scores[1 + i] = t + bh[0];
}

// --- online softmax: per-block (max, sumexp) partials ---
__global__ __launch_bounds__(256) void k_sm_part(const float* __restrict__ s, int n,
                                                 float2* __restrict__ part) {
  float m = -3.4e38f, sum = 0.f;
  for (int i = blockIdx.x * 256 + threadIdx.x; i < n; i += 256 * 256) {
    float x = s[i];
    if (x > m) { sum = sum * expf(m - x) + 1.f; m = x; }
    else sum += expf(x - m);
  }
  __shared__ float sm_m[256], sm_s[256];
  sm_m[threadIdx.x] = m; sm_s[threadIdx.x] = sum;
  __syncthreads();
  for (int o = 128; o > 0; o >>= 1) {
    if (threadIdx.x < o) {
      float m1 = sm_m[threadIdx.x], s1 = sm_s[threadIdx.x];
      float m2 = sm_m[threadIdx.x + o], s2 = sm_s[threadIdx.x + o];
      float M = fmaxf(m1, m2);
      sm_s[threadIdx.x] = s1 * expf(m1 - M) + s2 * expf(m2 - M);
      sm_m[threadIdx.x] = M;
    }
    __syncthreads();
  }
  if (threadIdx.x == 0) part[blockIdx.x] = make_float2(sm_m[0], sm_s[0]);
}

__global__ __launch_bounds__(256) void k_sm_fin(const float2* __restrict__ part,
                                                float* __restrict__ finals) {
  __shared__ float sm_m[256], sm_s[256];
  float2 p = part[threadIdx.x];
  sm_m[threadIdx.x] = p.x; sm_s[threadIdx.x] = p.y;
  __syncthreads();
  for (int o = 128; o > 0; o >>= 1) {
    if (threadIdx.x < o) {
      float m1 = sm_m[threadIdx.x], s1 = sm_s[threadIdx.x];
      float m2 = sm_m[threadIdx.x + o], s2 = sm_s[threadIdx.x + o];
      float M = fmaxf(m1, m2);
      sm_s[threadIdx.x] = s1 * expf(m1 - M) + s2 * expf(m2 - M);
      sm_m[threadIdx.x] = M;
    }
    __syncthreads();
  }
  if (threadIdx.x == 0) { finals[0] = sm_m[0]; finals[1] = sm_s[0]; }
}

__global__ void k_sm_out(const float* __restrict__ s, int n,
                         const float* __restrict__ finals, float* __restrict__ out) {
  int i = blockIdx.x * 256 + threadIdx.x;
  if (i < n) out[i] = expf(s[i] - finals[0]) / finals[1];
}

extern "C" void kernel_launch(void* const* d_in, const int* in_sizes, int n_in,
                              void* d_out, int out_size, void* d_ws, size_t ws_size,
                              hipStream_t stream) {
  const float* x    = (const float*)d_in[0];
  const int*   ei   = (const int*)d_in[1];
  const float* W1   = (const float*)d_in[2];
  const float* b1   = (const float*)d_in[3];
  const float* W2   = (const float*)d_in[4];
  const float* b2   = (const float*)d_in[5];
  const float* Wh   = (const float*)d_in[6];
  const float* bh   = (const float*)d_in[7];
  const float* cash = (const float*)d_in[8];

  const int N = in_sizes[0] / 128;
  const int E = in_sizes[1] / 2;
  const int* src = ei;
  const int* dst = ei + E;
  const int nbuk = cdiv(N, 512);  // 196 for N=100000 (<= NBMAX)

  char* p = (char*)d_ws;
  float* dinv   = (float*)p; p += sizeof(float) * N;
  u16*   hWs1   = (u16*)p;   p += sizeof(u16) * (size_t)N * 32;
  u16*   hWs2   = (u16*)p;   p += sizeof(u16) * (size_t)N * 32;
  float* scores = (float*)p; p += sizeof(float) * (N + 1);
  float2* part  = (float2*)p; p += sizeof(float2) * 256;
  float* finals = (float*)p; p += sizeof(float) * 4;
  unsigned* gcur  = (unsigned*)p; p += sizeof(unsigned) * NBMAX;
  unsigned* bbase = (unsigned*)p; p += sizeof(unsigned) * NBMAX;
  int* rowptr = (int*)p; p += sizeof(int) * (N + 1);
  unsigned* ebuf = (unsigned*)p; p += sizeof(unsigned) * (size_t)nbuk * CAP;
  int* esrc   = (int*)p; p += sizeof(int) * (size_t)E;
  float* out = (float*)d_out;
  const int n = N + 1;

  // --- CSR build (coarse-bucket counting sort; shared by both layers) ---
  (void)hipMemsetAsync(gcur, 0, sizeof(unsigned) * NBMAX, stream);
  k_bin<<<cdiv(E, EPB), 256, 0, stream>>>(src, dst, gcur, ebuf, E, nbuk);
  k_bukscan<<<1, 256, 0, stream>>>(gcur, bbase, rowptr, nbuk, N);
  k_place<<<nbuk, 512, 0, stream>>>(gcur, ebuf, bbase, rowptr, dinv, esrc, N);

  // --- layer 1 (+ fused layer-2 transform) ---
  k_gemm1<<<cdiv(N, 256), 256, 0, stream>>>(x, W1, dinv, hWs1, N);
  k_gather_fuse<<<cdiv((long)N * 8, 256), 256, 0, stream>>>(
      esrc, rowptr, dinv, (const uint2*)hWs1, b1, W2, (uint2*)hWs2, N);

  // --- layer 2 gather + fused score head ---
  k_gather_score<<<cdiv((long)N * 8, 256), 256, 0, stream>>>(
      esrc, rowptr, dinv, (const uint2*)hWs2, b2, Wh, bh, cash, scores, N);

  // --- online softmax (3 kernels) ---
  k_sm_part<<<256, 256, 0, stream>>>(scores, n, part);
  k_sm_fin<<<1, 256, 0, stream>>>(part, finals);
  k_sm_out<<<cdiv(n, 256), 256, 0, stream>>>(scores, n, finals, out);
}